// Round 1
// baseline (2366.764 us; speedup 1.0000x reference)
//
#include <hip/hip_runtime.h>

// ---------- types ----------
typedef __bf16 bf16x8 __attribute__((ext_vector_type(8)));
typedef float  f32x4  __attribute__((ext_vector_type(4)));
typedef unsigned short u16x8 __attribute__((ext_vector_type(8)));
typedef unsigned short u16x4 __attribute__((ext_vector_type(4)));

__device__ __forceinline__ unsigned short f2bf(float f) {
    unsigned int u = __builtin_bit_cast(unsigned int, f);
    unsigned int r = (u + 0x7FFFu + ((u >> 16) & 1u)) >> 16;   // RNE
    return (unsigned short)r;
}
__device__ __forceinline__ float sigmoid_f(float x) { return 1.f / (1.f + __expf(-x)); }
__device__ __forceinline__ float tanh_f(float x) {
    float e = __expf(2.f * x);
    return 1.f - 2.f / (e + 1.f);
}

// ---------- generic bf16 MFMA GEMM:  C[m,n] = sum_k A[m,k] * B[n,k] + bias[n] ----------
// A: fp32 (converted in staging) or bf16(ushort). B: bf16(ushort), row-major (N,ldb).
// PERMUTE: output row gm = t*128+b  ->  stored at row (b*15 + t)   (final logits layout).
template<int BM, int BN, bool A_F32, bool OUT_BF16, bool PERMUTE>
__global__ __launch_bounds__(256) void gemm_bt(
    const void* __restrict__ Aptr, int lda,
    const unsigned short* __restrict__ B, int ldb,
    void* __restrict__ Cptr, int ldc,
    const float* __restrict__ bias, int K)
{
    constexpr int WM = BM / 2, WN = BN / 2;
    constexpr int RM = WM / 16, RN = WN / 16;
    __shared__ unsigned short As[BM][40];   // +pad to 40 (80B rows) -> conflict-light
    __shared__ unsigned short Bs[BN][40];
    const int tid = threadIdx.x;
    const int lane = tid & 63, wid = tid >> 6;
    const int wr = wid >> 1, wc = wid & 1;
    const int m0 = blockIdx.y * BM, n0 = blockIdx.x * BN;

    f32x4 acc[RM][RN];
    for (int i = 0; i < RM; i++)
        for (int j = 0; j < RN; j++) acc[i][j] = f32x4{0.f, 0.f, 0.f, 0.f};

    const int nAc = BM * 4;   // 8-elem chunks
    const int nBc = BN * 4;
    for (int kt = 0; kt < K; kt += 32) {
        for (int c = tid; c < nAc; c += 256) {
            int r = c >> 2, s = c & 3;
            int kk = kt + s * 8;
            if (A_F32) {
                const float* src = (const float*)Aptr + (size_t)(m0 + r) * lda + kk;
                f32x4 x0 = *(const f32x4*)src;
                f32x4 x1 = *(const f32x4*)(src + 4);
                u16x8 v;
                v[0] = f2bf(x0[0]); v[1] = f2bf(x0[1]); v[2] = f2bf(x0[2]); v[3] = f2bf(x0[3]);
                v[4] = f2bf(x1[0]); v[5] = f2bf(x1[1]); v[6] = f2bf(x1[2]); v[7] = f2bf(x1[3]);
                *(u16x8*)&As[r][s * 8] = v;
            } else {
                const unsigned short* src = (const unsigned short*)Aptr + (size_t)(m0 + r) * lda + kk;
                *(u16x8*)&As[r][s * 8] = *(const u16x8*)src;
            }
        }
        for (int c = tid; c < nBc; c += 256) {
            int r = c >> 2, s = c & 3;
            const unsigned short* src = B + (size_t)(n0 + r) * ldb + kt + s * 8;
            *(u16x8*)&Bs[r][s * 8] = *(const u16x8*)src;
        }
        __syncthreads();
        bf16x8 a[RM], b[RN];
        for (int i = 0; i < RM; i++)
            a[i] = *(const bf16x8*)&As[wr * WM + i * 16 + (lane & 15)][(lane >> 4) * 8];
        for (int j = 0; j < RN; j++)
            b[j] = *(const bf16x8*)&Bs[wc * WN + j * 16 + (lane & 15)][(lane >> 4) * 8];
        for (int i = 0; i < RM; i++)
            for (int j = 0; j < RN; j++)
                acc[i][j] = __builtin_amdgcn_mfma_f32_16x16x32_bf16(a[i], b[j], acc[i][j], 0, 0, 0);
        __syncthreads();
    }
    for (int i = 0; i < RM; i++)
        for (int j = 0; j < RN; j++) {
            int gn = n0 + wc * WN + j * 16 + (lane & 15);
            float bv = bias ? bias[gn] : 0.f;
            for (int rg = 0; rg < 4; rg++) {
                int gm = m0 + wr * WM + i * 16 + (lane >> 4) * 4 + rg;
                float val = acc[i][j][rg] + bv;
                size_t off;
                if (PERMUTE) off = ((size_t)(gm & 127) * 15 + (size_t)(gm >> 7)) * (size_t)ldc + gn;
                else         off = (size_t)gm * (size_t)ldc + gn;
                if (OUT_BF16) ((unsigned short*)Cptr)[off] = f2bf(val);
                else          ((float*)Cptr)[off] = val;
            }
        }
}

// ---------- fused attention: per-b block. e=tanh(q+keys)*vw+vb -> softmax -> context ----------
__global__ __launch_bounds__(256) void attn_kernel(
    const float* __restrict__ q,      // (128,512)
    const float* __restrict__ keys,   // (128,49,512)
    const float* __restrict__ feats,  // (128,49,512)
    const float* __restrict__ vw,     // (512)
    const float* __restrict__ vb1,    // scalar
    float* __restrict__ context)      // (128,512)
{
    const int b = blockIdx.x;
    const int tid = threadIdx.x;
    const int lane = tid & 63, w = tid >> 6;
    __shared__ float qs[512], vws[512], es[64], wsm[64];
    for (int i = tid; i < 512; i += 256) { qs[i] = q[b * 512 + i]; vws[i] = vw[i]; }
    __syncthreads();
    const float vb = vb1[0];
    for (int s = w; s < 49; s += 4) {
        const float* kp = keys + ((size_t)b * 49 + s) * 512 + lane * 8;
        f32x4 k0 = *(const f32x4*)kp;
        f32x4 k1 = *(const f32x4*)(kp + 4);
        int h0 = lane * 8;
        float acc = 0.f;
        acc += tanh_f(qs[h0 + 0] + k0[0]) * vws[h0 + 0];
        acc += tanh_f(qs[h0 + 1] + k0[1]) * vws[h0 + 1];
        acc += tanh_f(qs[h0 + 2] + k0[2]) * vws[h0 + 2];
        acc += tanh_f(qs[h0 + 3] + k0[3]) * vws[h0 + 3];
        acc += tanh_f(qs[h0 + 4] + k1[0]) * vws[h0 + 4];
        acc += tanh_f(qs[h0 + 5] + k1[1]) * vws[h0 + 5];
        acc += tanh_f(qs[h0 + 6] + k1[2]) * vws[h0 + 6];
        acc += tanh_f(qs[h0 + 7] + k1[3]) * vws[h0 + 7];
        for (int o = 1; o < 64; o <<= 1) acc += __shfl_xor(acc, o, 64);
        if (lane == 0) es[s] = acc + vb;
    }
    __syncthreads();
    if (w == 0) {
        float e = (lane < 49) ? es[lane] : -1e30f;
        float m = e;
        for (int o = 1; o < 64; o <<= 1) m = fmaxf(m, __shfl_xor(m, o, 64));
        float p = (lane < 49) ? __expf(e - m) : 0.f;
        float sum = p;
        for (int o = 1; o < 64; o <<= 1) sum += __shfl_xor(sum, o, 64);
        if (lane < 49) wsm[lane] = p / sum;
    }
    __syncthreads();
    for (int k = tid; k < 512; k += 256) {
        float c = 0.f;
        for (int s = 0; s < 49; s++) c += wsm[s] * feats[((size_t)b * 49 + s) * 512 + k];
        context[(size_t)b * 512 + k] = c;
    }
}

// ---------- fused GRU cell: 6 waves = {gi,gh} x 3 gates, 32x32 tile, then gate math ----------
__global__ __launch_bounds__(384) void gru_cell(
    const float* __restrict__ Ax,               // (128,512) input to gi
    const float* __restrict__ Ah,               // (128,512) h_old
    const unsigned short* __restrict__ Bgi,     // (1536,512) bf16
    const unsigned short* __restrict__ Bgh,     // (1536,512) bf16
    const float* __restrict__ gi_add, int gi_add_matrix, // matrix(128,1536) or vec(1536)
    const float* __restrict__ gh_add,           // vec(1536)
    float* __restrict__ h_out,                  // (128,512)
    unsigned short* __restrict__ h3_out)        // optional bf16 copy
{
    __shared__ unsigned short As[2][32][40];
    __shared__ unsigned short Bs[6][32][40];
    __shared__ float G[6][32][32];
    const int tid = threadIdx.x;
    const int lane = tid & 63, w = tid >> 6;
    const int n0 = blockIdx.x * 32, m0 = blockIdx.y * 32;

    f32x4 acc[2][2];
    acc[0][0] = f32x4{0.f,0.f,0.f,0.f}; acc[0][1] = f32x4{0.f,0.f,0.f,0.f};
    acc[1][0] = f32x4{0.f,0.f,0.f,0.f}; acc[1][1] = f32x4{0.f,0.f,0.f,0.f};

    for (int kt = 0; kt < 512; kt += 32) {
        for (int c = tid; c < 1024; c += 384) {
            if (c < 256) {
                int mi = c >> 7, cc = c & 127;
                int r = cc >> 2, s = cc & 3;
                const float* src = (mi ? Ah : Ax) + (size_t)(m0 + r) * 512 + kt + s * 8;
                f32x4 x0 = *(const f32x4*)src;
                f32x4 x1 = *(const f32x4*)(src + 4);
                u16x8 v;
                v[0] = f2bf(x0[0]); v[1] = f2bf(x0[1]); v[2] = f2bf(x0[2]); v[3] = f2bf(x0[3]);
                v[4] = f2bf(x1[0]); v[5] = f2bf(x1[1]); v[6] = f2bf(x1[2]); v[7] = f2bf(x1[3]);
                *(u16x8*)&As[mi][r][s * 8] = v;
            } else {
                int c2 = c - 256;
                int bi = c2 >> 7, cc = c2 & 127;
                int r = cc >> 2, s = cc & 3;
                int grow = (bi % 3) * 512 + n0 + r;
                const unsigned short* src = (bi < 3 ? Bgi : Bgh) + (size_t)grow * 512 + kt + s * 8;
                *(u16x8*)&Bs[bi][r][s * 8] = *(const u16x8*)src;
            }
        }
        __syncthreads();
        const int ai = (w < 3) ? 0 : 1;
        bf16x8 a0 = *(const bf16x8*)&As[ai][(lane & 15)][(lane >> 4) * 8];
        bf16x8 a1 = *(const bf16x8*)&As[ai][16 + (lane & 15)][(lane >> 4) * 8];
        bf16x8 b0 = *(const bf16x8*)&Bs[w][(lane & 15)][(lane >> 4) * 8];
        bf16x8 b1 = *(const bf16x8*)&Bs[w][16 + (lane & 15)][(lane >> 4) * 8];
        acc[0][0] = __builtin_amdgcn_mfma_f32_16x16x32_bf16(a0, b0, acc[0][0], 0, 0, 0);
        acc[0][1] = __builtin_amdgcn_mfma_f32_16x16x32_bf16(a0, b1, acc[0][1], 0, 0, 0);
        acc[1][0] = __builtin_amdgcn_mfma_f32_16x16x32_bf16(a1, b0, acc[1][0], 0, 0, 0);
        acc[1][1] = __builtin_amdgcn_mfma_f32_16x16x32_bf16(a1, b1, acc[1][1], 0, 0, 0);
        __syncthreads();
    }
    for (int i = 0; i < 2; i++)
        for (int j = 0; j < 2; j++)
            for (int rg = 0; rg < 4; rg++) {
                int row = i * 16 + (lane >> 4) * 4 + rg;
                int col = j * 16 + (lane & 15);
                G[w][row][col] = acc[i][j][rg];
            }
    __syncthreads();
    for (int e = tid; e < 1024; e += 384) {
        int r = e >> 5, c = e & 31;
        int gb = m0 + r, hc = n0 + c;
        float gir, giz, gin;
        if (gi_add_matrix) {
            const float* ga = gi_add + (size_t)gb * 1536;
            gir = G[0][r][c] + ga[hc];
            giz = G[1][r][c] + ga[512 + hc];
            gin = G[2][r][c] + ga[1024 + hc];
        } else {
            gir = G[0][r][c] + gi_add[hc];
            giz = G[1][r][c] + gi_add[512 + hc];
            gin = G[2][r][c] + gi_add[1024 + hc];
        }
        float ghr = G[3][r][c] + gh_add[hc];
        float ghz = G[4][r][c] + gh_add[512 + hc];
        float ghn = G[5][r][c] + gh_add[1024 + hc];
        float rg_ = sigmoid_f(gir + ghr);
        float z   = sigmoid_f(giz + ghz);
        float n   = tanh_f(gin + rg_ * ghn);
        float hp  = Ah[(size_t)gb * 512 + hc];
        float hn  = (1.f - z) * n + z * hp;
        h_out[(size_t)gb * 512 + hc] = hn;
        if (h3_out) h3_out[(size_t)gb * 512 + hc] = f2bf(hn);
    }
}

// ---------- small helper kernels ----------
__global__ void cvt_f32_bf16(const float* __restrict__ s, unsigned short* __restrict__ d, int n4) {
    int i = blockIdx.x * 256 + threadIdx.x;
    if (i >= n4) return;
    f32x4 v = *(const f32x4*)(s + (size_t)i * 4);
    u16x4 o;
    o[0] = f2bf(v[0]); o[1] = f2bf(v[1]); o[2] = f2bf(v[2]); o[3] = f2bf(v[3]);
    *(u16x4*)(d + (size_t)i * 4) = o;
}

// fc0_w (512,512) -> transposed bf16: dst[k*512+h] = src[h*512+k]
__global__ __launch_bounds__(256) void transpose_cvt(const float* __restrict__ src, unsigned short* __restrict__ dst) {
    __shared__ float tile[32][33];
    int bx = blockIdx.x, by = blockIdx.y;
    int lx = threadIdx.x & 31, ly = threadIdx.x >> 5;
    for (int yy = ly; yy < 32; yy += 8)
        tile[yy][lx] = src[(size_t)(by * 32 + yy) * 512 + bx * 32 + lx];
    __syncthreads();
    for (int yy = ly; yy < 32; yy += 8)
        dst[(size_t)(bx * 32 + yy) * 512 + by * 32 + lx] = f2bf(tile[lx][yy]);
}

// out[i] = bih0[i] + sum_j wih0[i,512+j]*fc0_b[j]   (i<1536) ; grid 384 x 256
__global__ __launch_bounds__(256) void bias0_kernel(
    const float* __restrict__ wih0, const float* __restrict__ fc0_b,
    const float* __restrict__ bih0, float* __restrict__ out)
{
    int w = threadIdx.x >> 6, lane = threadIdx.x & 63;
    int i = blockIdx.x * 4 + w;
    const float* row = wih0 + (size_t)i * 1024 + 512;
    float acc = 0.f;
    for (int j = lane; j < 512; j += 64) acc += row[j] * fc0_b[j];
    for (int o = 1; o < 64; o <<= 1) acc += __shfl_xor(acc, o, 64);
    if (lane == 0) out[i] = acc + bih0[i];
}

// xe row r=t*128+b : bf16(emb[captions[b,t]])
__global__ void gather_emb(const float* __restrict__ emb, const int* __restrict__ captions,
                           unsigned short* __restrict__ xe) {
    int row = blockIdx.x;
    int t = row >> 7, b = row & 127;
    int tok = captions[b * 16 + t];
    const float* src = emb + (size_t)tok * 512;
    unsigned short* dst = xe + (size_t)row * 512;
    for (int e = threadIdx.x; e < 512; e += blockDim.x) dst[e] = f2bf(src[e]);
}

// ---------- launch ----------
extern "C" void kernel_launch(void* const* d_in, const int* in_sizes, int n_in,
                              void* d_out, int out_size, void* d_ws, size_t ws_size,
                              hipStream_t stream) {
    const float* features = (const float*)d_in[0];
    const int*   captions = (const int*)d_in[1];
    const float* emb    = (const float*)d_in[2];
    const float* fc1_w  = (const float*)d_in[3];
    const float* fc1_b  = (const float*)d_in[4];
    const float* fc0_w  = (const float*)d_in[5];
    const float* fc0_b  = (const float*)d_in[6];
    const float* wq     = (const float*)d_in[7];
    const float* bq     = (const float*)d_in[8];
    const float* wk     = (const float*)d_in[9];
    const float* bk     = (const float*)d_in[10];
    const float* v_w    = (const float*)d_in[11];
    const float* v_b    = (const float*)d_in[12];
    const float* wih0   = (const float*)d_in[13];
    const float* whh0   = (const float*)d_in[14];
    const float* bih0   = (const float*)d_in[15];
    const float* bhh0   = (const float*)d_in[16];
    const float* wih_r  = (const float*)d_in[17];
    const float* whh_r  = (const float*)d_in[18];
    const float* bih_r  = (const float*)d_in[19];
    const float* bhh_r  = (const float*)d_in[20];
    const float* fc2_w  = (const float*)d_in[21];
    const float* fc2_b  = (const float*)d_in[22];
    float* out = (float*)d_out;

    char* p = (char*)d_ws;
    auto alloc = [&](size_t bytes) { void* r = (void*)p; p += (bytes + 255) & ~(size_t)255; return r; };
    unsigned short* wq_bf   = (unsigned short*)alloc(262144 * 2);
    unsigned short* wk_bf   = (unsigned short*)alloc(262144 * 2);
    unsigned short* fc1_bf  = (unsigned short*)alloc(262144 * 2);
    unsigned short* wih0_bf = (unsigned short*)alloc(1572864 * 2);
    unsigned short* whh0_bf = (unsigned short*)alloc(786432 * 2);
    unsigned short* wihr_bf = (unsigned short*)alloc(2359296 * 2);
    unsigned short* whhr_bf = (unsigned short*)alloc(2359296 * 2);
    unsigned short* fc2_bf  = (unsigned short*)alloc(16384000 * 2);
    unsigned short* fc0T_bf = (unsigned short*)alloc(262144 * 2);
    unsigned short* Wc_bf   = (unsigned short*)alloc(786432 * 2);
    float*          bias0   = (float*)alloc(1536 * 4);
    unsigned short* xe_bf   = (unsigned short*)alloc(983040 * 2);
    unsigned short* x_bf    = (unsigned short*)alloc(983040 * 2);
    float*          gi_x    = (float*)alloc(2949120 * 4);   // (15,128,1536)
    float*          keys    = (float*)alloc(3211264 * 4);   // (128,49,512)
    float*          hA      = (float*)alloc(262144 * 4);    // (4,128,512)
    float*          hB      = (float*)alloc(262144 * 4);
    float*          qbuf    = (float*)alloc(65536 * 4);
    float*          ctxbuf  = (float*)alloc(65536 * 4);
    unsigned short* h3all   = (unsigned short*)alloc(983040 * 2); // (15,128,512)

    hipMemsetAsync(hA, 0, 262144 * 4, stream);

    auto cvt = [&](const float* s, unsigned short* d, int n) {
        int n4 = n / 4;
        cvt_f32_bf16<<<(n4 + 255) / 256, 256, 0, stream>>>(s, d, n4);
    };
    cvt(wq, wq_bf, 262144);
    cvt(wk, wk_bf, 262144);
    cvt(fc1_w, fc1_bf, 262144);
    cvt(wih0, wih0_bf, 1572864);
    cvt(whh0, whh0_bf, 786432);
    cvt(wih_r, wihr_bf, 2359296);
    cvt(whh_r, whhr_bf, 2359296);
    cvt(fc2_w, fc2_bf, 16384000);
    transpose_cvt<<<dim3(16, 16), 256, 0, stream>>>(fc0_w, fc0T_bf);
    bias0_kernel<<<384, 256, 0, stream>>>(wih0, fc0_b, bih0, bias0);
    gather_emb<<<1920, 256, 0, stream>>>(emb, captions, xe_bf);

    // x = xe @ fc1^T + fc1_b  (bf16 out)
    gemm_bt<64, 64, false, true, false><<<dim3(8, 30), 256, 0, stream>>>(
        xe_bf, 512, fc1_bf, 512, x_bf, 512, fc1_b, 512);
    // Wc = wih0[:,512:] @ fc0T^T   (1536,512) bf16
    gemm_bt<64, 64, false, true, false><<<dim3(8, 24), 256, 0, stream>>>(
        wih0_bf + 512, 1024, fc0T_bf, 512, Wc_bf, 512, nullptr, 512);
    // gi_x = x @ wih0[:, :512]^T + (bih0 + wih0_c@fc0_b)
    gemm_bt<64, 64, false, false, false><<<dim3(24, 30), 256, 0, stream>>>(
        x_bf, 512, wih0_bf, 1024, gi_x, 1536, bias0, 512);
    // keys_proj = features @ wk^T + bk
    gemm_bt<64, 64, true, false, false><<<dim3(8, 98), 256, 0, stream>>>(
        features, 512, wk_bf, 512, keys, 512, bk, 512);

    for (int t = 0; t < 15; t++) {
        float* hold = (t & 1) ? hB : hA;
        float* hnew = (t & 1) ? hA : hB;
        // q = h[3] @ wq^T + bq
        gemm_bt<64, 64, true, false, false><<<dim3(8, 2), 256, 0, stream>>>(
            hold + 3 * 65536, 512, wq_bf, 512, qbuf, 512, bq, 512);
        attn_kernel<<<128, 256, 0, stream>>>(qbuf, keys, features, v_w, v_b, ctxbuf);
        // GRU0: gi = gi_x[t] + context@Wc^T ; gh = h0@whh0^T + bhh0
        gru_cell<<<dim3(16, 4), 384, 0, stream>>>(
            ctxbuf, hold, Wc_bf, whh0_bf,
            gi_x + (size_t)t * 128 * 1536, 1, bhh0,
            hnew, nullptr);
        // GRU1..3
        for (int l = 1; l < 4; l++) {
            gru_cell<<<dim3(16, 4), 384, 0, stream>>>(
                hnew + (l - 1) * 65536, hold + l * 65536,
                wihr_bf + (size_t)(l - 1) * 786432, whhr_bf + (size_t)(l - 1) * 786432,
                bih_r + (l - 1) * 1536, 0, bhh_r + (l - 1) * 1536,
                hnew + l * 65536,
                (l == 3) ? (h3all + (size_t)t * 65536) : nullptr);
        }
    }
    // logits: (1920,512)@(32000,512)^T + fc2_b, permuted rows (t*128+b) -> (b*15+t)
    gemm_bt<128, 128, false, false, true><<<dim3(250, 15), 256, 0, stream>>>(
        h3all, 512, fc2_bf, 512, out, 32000, fc2_b, 512);
}